// Round 1
// baseline (667.208 us; speedup 1.0000x reference)
//
#include <hip/hip_runtime.h>

#define C 19
#define DCH 128
#define HWSZ 65536
#define TPB 256

// ws float offsets
#define WS_SUMS  0      // 2432 floats: sums[d*19+c]
#define WS_CNT   2432   // 19
#define WS_VAR   2451   // 19
#define WS_MEANS 2560   // 2432: meansT[d*19+c]
#define WS_VALID 4992   // 19
#define WS_SCAL  5011   // 3: loss_reg, loss_dist, t
#define WS_ZERO_END 2470

__global__ void k0_init(float* __restrict__ ws) {
    int i = blockIdx.x * blockDim.x + threadIdx.x;
    if (i < WS_ZERO_END) ws[i] = 0.f;
}

// Pass 1: per-class sums + counts. 512 blocks, 1024 pixels/block (4/thread via float4).
__global__ __launch_bounds__(TPB) void k1_sums(const float* __restrict__ feats,
                                               const int* __restrict__ labels,
                                               float* __restrict__ ws) {
    __shared__ float lsum[DCH * C];
    __shared__ float lcnt[C];
    int t = threadIdx.x;
    for (int i = t; i < DCH * C; i += TPB) lsum[i] = 0.f;
    if (t < C) lcnt[t] = 0.f;
    __syncthreads();

    int g = blockIdx.x;           // 512 = 8 images * 64 groups
    int b = g >> 6;
    int p = ((g & 63) << 10) + (t << 2);
    const int4 lab4 = *reinterpret_cast<const int4*>(labels + b * HWSZ + p);
    if (lab4.x >= 0) atomicAdd(&lcnt[lab4.x], 1.f);
    if (lab4.y >= 0) atomicAdd(&lcnt[lab4.y], 1.f);
    if (lab4.z >= 0) atomicAdd(&lcnt[lab4.z], 1.f);
    if (lab4.w >= 0) atomicAdd(&lcnt[lab4.w], 1.f);

    const float* fb = feats + (size_t)b * DCH * HWSZ + p;
#pragma unroll 8
    for (int d = 0; d < DCH; ++d) {
        float4 x = *reinterpret_cast<const float4*>(fb + (size_t)d * HWSZ);
        int off = d * C;
        if (lab4.x >= 0) atomicAdd(&lsum[off + lab4.x], x.x);
        if (lab4.y >= 0) atomicAdd(&lsum[off + lab4.y], x.y);
        if (lab4.z >= 0) atomicAdd(&lsum[off + lab4.z], x.z);
        if (lab4.w >= 0) atomicAdd(&lsum[off + lab4.w], x.w);
    }
    __syncthreads();
    for (int i = t; i < DCH * C; i += TPB) atomicAdd(&ws[WS_SUMS + i], lsum[i]);
    if (t < C) atomicAdd(&ws[WS_CNT + t], lcnt[t]);
}

// Pass 2: means, valid mask, loss_reg, loss_dist, t. Single block.
__global__ __launch_bounds__(TPB) void k2_means(float* __restrict__ ws) {
    __shared__ float lm[DCH * C];
    __shared__ float lcnt[C];
    __shared__ float lvalid[C];
    __shared__ float lreg;
    __shared__ float ldist;
    __shared__ int   llast;
    __shared__ float ltv;
    int t = threadIdx.x;
    if (t == 0) { lreg = 0.f; ldist = 0.f; }
    if (t < C) {
        float c = ws[WS_CNT + t];
        lcnt[t] = c;
        lvalid[t] = (c > 100.f) ? 1.f : 0.f;
    }
    __syncthreads();
    for (int i = t; i < DCH * C; i += TPB) {
        int c = i % C;
        float m = ws[WS_SUMS + i] / fmaxf(lcnt[c], 1.f);
        lm[i] = m;
        ws[WS_MEANS + i] = m;
    }
    if (t == 0) {
        float tv = 0.f; int last = -1;
        for (int c2 = 0; c2 < C; ++c2) if (lvalid[c2] > 0.5f) { tv += 1.f; last = c2; }
        ltv = tv; llast = last;
    }
    __syncthreads();
    // loss_reg: per-class mean norms
    if (t < C) {
        float s = 0.f;
        for (int d = 0; d < DCH; ++d) { float m = lm[d * C + t]; s += m * m; }
        float nrm = (s > 0.f) ? sqrtf(s) : 0.f;
        if (lvalid[t] > 0.5f) atomicAdd(&lreg, nrm);
    }
    // loss_dist: faithful buggy double loop (a over valid, b over valid & != last, incl a==b)
    for (int pr = t; pr < C * C; pr += TPB) {
        int a = pr / C, b2 = pr % C;
        if (lvalid[a] > 0.5f && lvalid[b2] > 0.5f && b2 != llast) {
            float s = 0.f;
            for (int d = 0; d < DCH; ++d) {
                float df = lm[d * C + a] - lm[d * C + b2];
                s += df * df;
            }
            float nrm = (s > 0.f) ? sqrtf(s) : 0.f;
            float hd = fmaxf(3.0f - nrm, 0.f);   // 2*DELTA_D = 3.0
            atomicAdd(&ldist, hd * hd);
        }
    }
    __syncthreads();
    if (t < C) ws[WS_VALID + t] = lvalid[t];
    if (t == 0) {
        ws[WS_SCAL + 0] = lreg;
        ws[WS_SCAL + 1] = ldist;
        ws[WS_SCAL + 2] = ltv;
    }
}

// Pass 3: per-pixel hinged distance to class mean, per-class accumulate.
__global__ __launch_bounds__(TPB) void k3_var(const float* __restrict__ feats,
                                              const int* __restrict__ labels,
                                              float* __restrict__ ws) {
    __shared__ float lm[DCH * C];
    __shared__ float lvalid[C];
    __shared__ float lvar[C];
    int t = threadIdx.x;
    for (int i = t; i < DCH * C; i += TPB) lm[i] = ws[WS_MEANS + i];
    if (t < C) { lvalid[t] = ws[WS_VALID + t]; lvar[t] = 0.f; }
    __syncthreads();

    int g = blockIdx.x;
    int b = g >> 6;
    int p = ((g & 63) << 10) + (t << 2);
    const int4 lab4 = *reinterpret_cast<const int4*>(labels + b * HWSZ + p);
    int l0 = lab4.x < 0 ? 0 : lab4.x;
    int l1 = lab4.y < 0 ? 0 : lab4.y;
    int l2 = lab4.z < 0 ? 0 : lab4.z;
    int l3 = lab4.w < 0 ? 0 : lab4.w;
    const float* fb = feats + (size_t)b * DCH * HWSZ + p;
    float a0 = 0.f, a1 = 0.f, a2 = 0.f, a3 = 0.f;
#pragma unroll 8
    for (int d = 0; d < DCH; ++d) {
        float4 x = *reinterpret_cast<const float4*>(fb + (size_t)d * HWSZ);
        int off = d * C;
        float d0 = x.x - lm[off + l0]; a0 = fmaf(d0, d0, a0);
        float d1 = x.y - lm[off + l1]; a1 = fmaf(d1, d1, a1);
        float d2 = x.z - lm[off + l2]; a2 = fmaf(d2, d2, a2);
        float d3 = x.w - lm[off + l3]; a3 = fmaf(d3, d3, a3);
    }
    auto hinge2 = [&](float a, int rawlab, int l) -> float {
        float nrm = (a > 0.f) ? sqrtf(a) : 0.f;
        float h = fmaxf(nrm - 0.5f, 0.f);      // DELTA_V = 0.5
        float v = h * h;
        return (rawlab >= 0 && lvalid[l] > 0.5f) ? v : 0.f;
    };
    atomicAdd(&lvar[l0], hinge2(a0, lab4.x, l0));
    atomicAdd(&lvar[l1], hinge2(a1, lab4.y, l1));
    atomicAdd(&lvar[l2], hinge2(a2, lab4.z, l2));
    atomicAdd(&lvar[l3], hinge2(a3, lab4.w, l3));
    __syncthreads();
    if (t < C) atomicAdd(&ws[WS_VAR + t], lvar[t]);
}

// Pass 4: final scalar.
__global__ void k4_final(const float* __restrict__ ws, float* __restrict__ out) {
    if (threadIdx.x == 0) {
        float loss_var = 0.f;
        for (int c = 0; c < C; ++c) {
            float cnt = ws[WS_CNT + c];
            float v = ws[WS_VAR + c] / fmaxf(cnt, 1.f);
            if (ws[WS_VALID + c] > 0.5f) loss_var += v;
        }
        float reg  = ws[WS_SCAL + 0];
        float dist = ws[WS_SCAL + 1];
        float tv   = ws[WS_SCAL + 2];
        // ALPHA=1, BETA=1, GAMMA=0.001
        float loss = loss_var / tv + dist / (tv * (tv - 1.0f)) + 0.001f * reg / tv;
        out[0] = loss;
    }
}

extern "C" void kernel_launch(void* const* d_in, const int* in_sizes, int n_in,
                              void* d_out, int out_size, void* d_ws, size_t ws_size,
                              hipStream_t stream) {
    const float* feats  = (const float*)d_in[0];
    const int*   labels = (const int*)d_in[1];
    float* ws  = (float*)d_ws;
    float* out = (float*)d_out;

    hipLaunchKernelGGL(k0_init,  dim3((WS_ZERO_END + 255) / 256), dim3(256), 0, stream, ws);
    hipLaunchKernelGGL(k1_sums,  dim3(512), dim3(TPB), 0, stream, feats, labels, ws);
    hipLaunchKernelGGL(k2_means, dim3(1),   dim3(TPB), 0, stream, ws);
    hipLaunchKernelGGL(k3_var,   dim3(512), dim3(TPB), 0, stream, feats, labels, ws);
    hipLaunchKernelGGL(k4_final, dim3(1),   dim3(64),  0, stream, ws, out);
}